// Round 12
// baseline (308.177 us; speedup 1.0000x reference)
//
#include <hip/hip_runtime.h>

typedef unsigned short u16;
typedef __attribute__((ext_vector_type(8))) __bf16 bf16x8;
typedef __attribute__((ext_vector_type(4))) float f32x4;

#define LSEQ 4096
#define DMODEL 1024
#define DINNER 2048

__device__ __forceinline__ float bf2f(u16 u) {
  union { unsigned u; float f; } v; v.u = ((unsigned)u) << 16; return v.f;
}
__device__ __forceinline__ u16 f2bf(float f) {
  union { float f; unsigned u; } v; v.f = f;
  unsigned r = v.u + 0x7fffu + ((v.u >> 16) & 1u);
  return (u16)(r >> 16);
}
__device__ __forceinline__ void gload_lds16(const void* g, void* l) {
  __builtin_amdgcn_global_load_lds(
      (__attribute__((address_space(1))) void*)(unsigned long long)g,
      (__attribute__((address_space(3))) void*)(unsigned int)(unsigned long long)l,
      16, 0, 0);
}
__device__ __forceinline__ float sigmoidf_(float v) { return 1.f / (1.f + __expf(-v)); }

// bijective XCD swizzle (nwg % 8 == 0)
__device__ __forceinline__ void swz_block(int gx, int& bn, int& bm) {
  int lin = blockIdx.x + gridDim.x * blockIdx.y;
  int q = (gridDim.x * gridDim.y) >> 3;
  int s = (lin & 7) * q + (lin >> 3);
  bn = s % gx;
  bm = s / gx;
}

// phase boundary: barrier + scheduling fence (no instr may cross)
#define SBAR { __builtin_amdgcn_s_barrier(); __builtin_amdgcn_sched_barrier(0); }

// ---------------- fused weight transpose+cast (4 segments) + LayerNorm rows ----------------
__global__ __launch_bounds__(256) void tc_ln_all(const float* __restrict__ W_in,
                                                 const float* __restrict__ W_x,
                                                 const float* __restrict__ W_dt,
                                                 const float* __restrict__ W_out,
                                                 u16* __restrict__ o0, u16* __restrict__ o1,
                                                 u16* __restrict__ o2, u16* __restrict__ o3,
                                                 const float* __restrict__ x,
                                                 const float* __restrict__ nw,
                                                 const float* __restrict__ nb,
                                                 u16* __restrict__ xn_out) {
  int id = blockIdx.x;
  int t = threadIdx.x;
  if (id >= 6528) {
    int row = id - 6528;
    const float* xr = x + (size_t)row * DMODEL;
    float4 v = ((const float4*)xr)[t];
    float s = v.x + v.y + v.z + v.w;
    float s2 = v.x * v.x + v.y * v.y + v.z * v.z + v.w * v.w;
    for (int off = 32; off; off >>= 1) {
      s += __shfl_down(s, off);
      s2 += __shfl_down(s2, off);
    }
    __shared__ float ls[4], ls2[4];
    int wid = t >> 6;
    if ((t & 63) == 0) { ls[wid] = s; ls2[wid] = s2; }
    __syncthreads();
    s = ls[0] + ls[1] + ls[2] + ls[3];
    s2 = ls2[0] + ls2[1] + ls2[2] + ls2[3];
    float mu = s * (1.f / DMODEL);
    float var = s2 * (1.f / DMODEL) - mu * mu;
    float rs = rsqrtf(var + 1e-5f);
    float4 wv = ((const float4*)nw)[t];
    float4 bv = ((const float4*)nb)[t];
    unsigned p0 = (unsigned)f2bf((v.x - mu) * rs * wv.x + bv.x) |
                  ((unsigned)f2bf((v.y - mu) * rs * wv.y + bv.y) << 16);
    unsigned p1 = (unsigned)f2bf((v.z - mu) * rs * wv.z + bv.z) |
                  ((unsigned)f2bf((v.w - mu) * rs * wv.w + bv.w) << 16);
    ((uint2*)(xn_out + (size_t)row * DMODEL))[t] = make_uint2(p0, p1);
    return;
  }
  __shared__ float tile[32][33];
  const float* in;
  u16* out;
  int K, N, Npad, gx, bx;
  if (id < 4096)      { in = W_in;  out = o0; K = 1024; N = 4096; Npad = 4096; gx = 128; bx = id; }
  else if (id < 4352) { in = W_x;   out = o1; K = 2048; N = 96;   Npad = 128;  gx = 4;   bx = id - 4096; }
  else if (id < 4480) { in = W_dt;  out = o2; K = 64;   N = 2048; Npad = 2048; gx = 64;  bx = id - 4352; }
  else                { in = W_out; out = o3; K = 2048; N = 1024; Npad = 1024; gx = 32;  bx = id - 4480; }
  int n0 = (bx % gx) * 32, k0 = (bx / gx) * 32;
  int tx = t & 31, ty = t >> 5;
  for (int i = ty; i < 32; i += 8) {
    int k = k0 + i, n = n0 + tx;
    tile[i][tx] = (k < K && n < N) ? in[(size_t)k * N + n] : 0.f;
  }
  __syncthreads();
  for (int i = ty; i < 32; i += 8) {
    int n = n0 + i, k = k0 + tx;
    if (n < Npad && k < K) out[(size_t)n * K + k] = f2bf(tile[tx][i]);
  }
}

// ---------------- common staging helper: 8 rows x 64k, swizzle key = row&7 ----------------
__device__ __forceinline__ void stage8(const u16* grow0, int ld, int kcol0,
                                       u16* lds_u, int ln) {
  int rr = ln >> 3, kb = ln & 7;
  gload_lds16(grow0 + (size_t)rr * ld + kcol0 + ((kb ^ rr) << 3), lds_u);
}

// =====================================================================================
// gemm8p: 256x256, BK=64, 128KB LDS, 1 block/CU, 2 barriers/K-tile (round-11 verified).
// __launch_bounds__(512,2): do NOT raise min-waves (4/EU caps 128 VGPR -> acc spills).
// =====================================================================================
#define LDA_F(mh, BUF)                                                             \
  _Pragma("unroll") for (int mf = 0; mf < 4; ++mf) {                               \
    av[mf][0] = *(const bf16x8*)(qA0 + (BUF) * 16384 + ((mh) * 64 + mf * 16) * 64); \
    av[mf][1] = *(const bf16x8*)(qA1 + (BUF) * 16384 + ((mh) * 64 + mf * 16) * 64); \
  }

#define LDB_F(nh, BUF)                                                             \
  _Pragma("unroll") for (int nf = 0; nf < 2; ++nf) {                               \
    bb[nh][nf][0] = *(const bf16x8*)(qB0 + (BUF) * 16384 + ((nh) * 32 + nf * 16) * 64); \
    bb[nh][nf][1] = *(const bf16x8*)(qB1 + (BUF) * 16384 + ((nh) * 32 + nf * 16) * 64); \
  }

#define MFMA_Q(mh, nh)                                                             \
  __builtin_amdgcn_s_setprio(1);                                                   \
  _Pragma("unroll") for (int mf = 0; mf < 4; ++mf)                                 \
  _Pragma("unroll") for (int nf = 0; nf < 2; ++nf)                                 \
  _Pragma("unroll") for (int kk = 0; kk < 2; ++kk)                                 \
    acc[(mh) * 4 + mf][(nh) * 2 + nf] = __builtin_amdgcn_mfma_f32_16x16x32_bf16(   \
        av[mf][kk], bb[nh][nf][kk], acc[(mh) * 4 + mf][(nh) * 2 + nf], 0, 0, 0);   \
  __builtin_amdgcn_s_setprio(0);

#define STAGE_A(unit, kt, buf)                                                     \
  _Pragma("unroll") for (int c = 0; c < 2; ++c) {                                  \
    int g = w * 2 + c;                                                             \
    int r0 = ((g < 8) ? g * 8 : (g - 8) * 8 + 128) + (unit) * 64;                  \
    stage8(Ag + (size_t)r0 * ldK, ldK, (kt) * 64, LA + (buf) * 16384 + r0 * 64, ln); \
  }

#define STAGE_B(half, kt, buf)                                                     \
  _Pragma("unroll") for (int c = 0; c < 2; ++c) {                                  \
    int g = w * 2 + c;                                                             \
    int r0 = (g >> 2) * 64 + (half) * 32 + (g & 3) * 8;                            \
    stage8(Bg + (size_t)r0 * ldK, ldK, (kt) * 64, LB + (buf) * 16384 + r0 * 64, ln); \
  }

#define PHASES8P(T_, B0_, B1_)                                                     \
  {                                                                                \
    int kt1 = ((T_) + 1 < NT) ? (T_) + 1 : NT - 1;                                 \
    int kt2 = ((T_) + 2 < NT) ? (T_) + 2 : NT - 1;                                 \
    LDA_F(0, B0_); LDB_F(0, B0_); LDB_F(1, B0_);                                   \
    STAGE_A(1, kt1, B1_);                                                          \
    MFMA_Q(0, 0);                                                                  \
    MFMA_Q(0, 1);                                                                  \
    SBAR                                                                           \
    LDA_F(1, B0_);                                                                 \
    STAGE_A(0, kt2, B0_);                                                          \
    STAGE_B(0, kt2, B0_);                                                          \
    STAGE_B(1, kt2, B0_);                                                          \
    asm volatile("s_waitcnt vmcnt(6)" ::: "memory");                               \
    MFMA_Q(1, 1);                                                                  \
    MFMA_Q(1, 0);                                                                  \
    SBAR                                                                           \
  }

template <int OUT_BF16, int EPI>  // EPI: 1 = +aux residual (f32), 2 = silu col>=cthresh
__global__ __launch_bounds__(512, 2) void gemm8p(const u16* __restrict__ A,
                                                 const u16* __restrict__ Bt,
                                                 void* __restrict__ Cout,
                                                 const float* __restrict__ aux,
                                                 int M, int N, int K, int cthresh) {
  __shared__ alignas(16) u16 lds[65536];
  u16* LA = lds;
  u16* LB = lds + 32768;
  int t = threadIdx.x;
  int w = t >> 6, ln = t & 63;
  int wm = w >> 2, wn = w & 3;
  int bn, bm;
  swz_block(gridDim.x, bn, bm);
  int lr = ln & 15, lq = ln >> 4, key = ln & 7;
  int ldK = K;
  int NT = K >> 6;
  const u16* Ag = A + (size_t)bm * 256 * ldK;
  const u16* Bg = Bt + (size_t)bn * 256 * ldK;
  const u16* qA0 = LA + (wm * 128 + lr) * 64 + ((lq ^ key) << 3);
  const u16* qA1 = LA + (wm * 128 + lr) * 64 + (((4 + lq) ^ key) << 3);
  const u16* qB0 = LB + (wn * 64 + lr) * 64 + ((lq ^ key) << 3);
  const u16* qB1 = LB + (wn * 64 + lr) * 64 + (((4 + lq) ^ key) << 3);
  f32x4 acc[8][4] = {};
  bf16x8 av[4][2], bb[2][2][2];

  STAGE_A(0, 0, 0); STAGE_B(0, 0, 0); STAGE_B(1, 0, 0); STAGE_A(1, 0, 0);
  int k1 = NT > 1 ? 1 : 0;
  STAGE_A(0, k1, 1); STAGE_B(0, k1, 1); STAGE_B(1, k1, 1);
  asm volatile("s_waitcnt vmcnt(6)" ::: "memory");
  SBAR

  for (int TT = 0; TT < NT; TT += 2) {  // NT is even (K multiple of 128)
    PHASES8P(TT, 0, 1)
    PHASES8P(TT + 1, 1, 0)
  }

  int crow0 = bm * 256 + wm * 128;
  int ccol0 = bn * 256 + wn * 64;
#pragma unroll
  for (int mf = 0; mf < 8; ++mf)
#pragma unroll
    for (int nf = 0; nf < 4; ++nf)
#pragma unroll
      for (int r = 0; r < 4; ++r) {
        int row = crow0 + mf * 16 + lq * 4 + r;
        int col = ccol0 + nf * 16 + lr;
        float v = acc[mf][nf][r];
        if (EPI == 1) v += aux[(size_t)row * N + col];
        if (EPI == 2 && col >= cthresh) v = v * sigmoidf_(v);
        if (OUT_BF16)
          ((u16*)Cout)[(size_t)row * N + col] = f2bf(v);
        else
          ((float*)Cout)[(size_t)row * N + col] = v;
      }
}

// =====================================================================================
// gemm128_res: BM=128 x BN=256, BK=64, 96KB LDS, 2 barriers/tile, residual fused, f32.
// =====================================================================================
#define LDA128(mh, BUF)                                                            \
  _Pragma("unroll") for (int mf2 = 0; mf2 < 2; ++mf2) {                            \
    av[mf2][0] = *(const bf16x8*)(rA0 + (BUF) * 8192 + ((mh) * 32 + mf2 * 16) * 64); \
    av[mf2][1] = *(const bf16x8*)(rA1 + (BUF) * 8192 + ((mh) * 32 + mf2 * 16) * 64); \
  }

#define LDB128(nh, BUF, B_)                                                        \
  _Pragma("unroll") for (int nf2 = 0; nf2 < 2; ++nf2) {                            \
    B_[nf2][0] = *(const bf16x8*)(rB0 + (BUF) * 16384 + ((nh) * 32 + nf2 * 16) * 64); \
    B_[nf2][1] = *(const bf16x8*)(rB1 + (BUF) * 16384 + ((nh) * 32 + nf2 * 16) * 64); \
  }

#define MFMA_Q128(mh, nh, B_)                                                      \
  __builtin_amdgcn_s_setprio(1);                                                   \
  _Pragma("unroll") for (int mf2 = 0; mf2 < 2; ++mf2)                              \
  _Pragma("unroll") for (int nf2 = 0; nf2 < 2; ++nf2)                              \
  _Pragma("unroll") for (int kk = 0; kk < 2; ++kk)                                 \
    acc[(mh) * 2 + mf2][(nh) * 2 + nf2] = __builtin_amdgcn_mfma_f32_16x16x32_bf16( \
        av[mf2][kk], B_[nf2][kk], acc[(mh) * 2 + mf2][(nh) * 2 + nf2], 0, 0, 0);   \
  __builtin_amdgcn_s_setprio(0);

#define STAGE_A128(unit, kt, buf)                                                  \
  {                                                                                \
    int r0 = (w >> 2) * 64 + (unit) * 32 + (w & 3) * 8;                            \
    stage8(Ag + (size_t)r0 * ldK, ldK, (kt) * 64, LA + (buf) * 8192 + r0 * 64, ln); \
  }

#define STAGE_B128(half, kt, buf)                                                  \
  _Pragma("unroll") for (int c = 0; c < 2; ++c) {                                  \
    int g = w * 2 + c;                                                             \
    int r0 = (g >> 2) * 64 + (half) * 32 + (g & 3) * 8;                            \
    stage8(Bg + (size_t)r0 * ldK, ldK, (kt) * 64, LB + (buf) * 16384 + r0 * 64, ln); \
  }

#define PHASES128(T_, B0_, B1_)                                                    \
  {                                                                                \
    int kt1 = ((T_) + 1 < NT) ? (T_) + 1 : NT - 1;                                 \
    int kt2 = ((T_) + 2 < NT) ? (T_) + 2 : NT - 1;                                 \
    LDA128(0, B0_);                                                                \
    LDB128(0, B0_, bbl);                                                           \
    LDB128(1, B0_, bbh);                                                           \
    STAGE_A128(1, kt1, B1_);                                                       \
    MFMA_Q128(0, 0, bbl);                                                          \
    MFMA_Q128(0, 1, bbh);                                                          \
    SBAR                                                                           \
    LDA128(1, B0_);                                                                \
    STAGE_A128(0, kt2, B0_);                                                       \
    STAGE_B128(0, kt2, B0_);                                                       \
    STAGE_B128(1, kt2, B0_);                                                       \
    asm volatile("s_waitcnt vmcnt(5)" ::: "memory");                               \
    MFMA_Q128(1, 1, bbh);                                                          \
    MFMA_Q128(1, 0, bbl);                                                          \
    SBAR                                                                           \
  }

__global__ __launch_bounds__(512, 2) void gemm128_res(const u16* __restrict__ A,
                                                      const u16* __restrict__ Bt,
                                                      float* __restrict__ Cout,
                                                      const float* __restrict__ res,
                                                      int M, int N, int K) {
  __shared__ alignas(16) u16 lds[49152];
  u16* LA = lds;
  u16* LB = lds + 16384;
  int t = threadIdx.x;
  int w = t >> 6, ln = t & 63;
  int wm = w >> 2, wn = w & 3;
  int bn, bm;
  swz_block(gridDim.x, bn, bm);
  int lr = ln & 15, lq = ln >> 4, key = ln & 7;
  int ldK = K;
  int NT = K >> 6;
  const u16* Ag = A + (size_t)bm * 128 * ldK;
  const u16* Bg = Bt + (size_t)bn * 256 * ldK;
  const u16* rA0 = LA + (wm * 64 + lr) * 64 + ((lq ^ key) << 3);
  const u16* rA1 = LA + (wm * 64 + lr) * 64 + (((4 + lq) ^ key) << 3);
  const u16* rB0 = LB + (wn * 64 + lr) * 64 + ((lq ^ key) << 3);
  const u16* rB1 = LB + (wn * 64 + lr) * 64 + (((4 + lq) ^ key) << 3);
  f32x4 acc[4][4] = {};
  bf16x8 av[2][2], bbl[2][2], bbh[2][2];

  STAGE_A128(0, 0, 0); STAGE_B128(0, 0, 0); STAGE_B128(1, 0, 0); STAGE_A128(1, 0, 0);
  int k1 = NT > 1 ? 1 : 0;
  STAGE_A128(0, k1, 1); STAGE_B128(0, k1, 1); STAGE_B128(1, k1, 1);
  asm volatile("s_waitcnt vmcnt(5)" ::: "memory");
  SBAR

  for (int TT = 0; TT < NT; TT += 2) {
    PHASES128(TT, 0, 1)
    PHASES128(TT + 1, 1, 0)
  }

  int crow0 = bm * 128 + wm * 64;
  int ccol0 = bn * 256 + wn * 64;
#pragma unroll
  for (int mf = 0; mf < 4; ++mf)
#pragma unroll
    for (int nf = 0; nf < 4; ++nf)
#pragma unroll
      for (int r = 0; r < 4; ++r) {
        int row = crow0 + mf * 16 + lq * 4 + r;
        int col = ccol0 + nf * 16 + lr;
        Cout[(size_t)row * N + col] = acc[mf][nf][r] + res[(size_t)row * N + col];
      }
}

// ---------------- 128x128 bf16 GEMM (small shapes) ----------------
template <int OUT_BF16, int EPI, int SPLITK>
__global__ __launch_bounds__(256) void gemm_bt(const u16* __restrict__ A,
                                               const u16* __restrict__ Bt,
                                               void* __restrict__ Cout,
                                               const float* __restrict__ aux,
                                               int M, int N, int K, int ld, int cthresh) {
  __shared__ alignas(16) u16 As[128 * 32];
  __shared__ alignas(16) u16 Bs[128 * 32];
  int t = threadIdx.x;
  int w = t >> 6, ln = t & 63;
  int wr = w >> 1, wc = w & 1;
  int bm = blockIdx.y, bn = blockIdx.x;
  int lr = ln & 15, lk = (ln >> 4) * 8;
  f32x4 acc[4][4] = {};
  int kz = SPLITK ? blockIdx.z * K : 0;
  const u16* Abase = A + (size_t)bm * 128 * ld + kz;
  const u16* Bbase = Bt + (size_t)bn * 128 * ld + kz;
  for (int k0 = 0; k0 < K; k0 += 32) {
#pragma unroll
    for (int c = 0; c < 2; ++c) {
      int chunk = w * 2 + c;
      int ee = chunk * 512 + ln * 8;
      int row = ee >> 5, col = ee & 31;
      gload_lds16(Abase + (size_t)row * ld + k0 + col, As + chunk * 512);
      gload_lds16(Bbase + (size_t)row * ld + k0 + col, Bs + chunk * 512);
    }
    __syncthreads();
    bf16x8 af[4], bfr[4];
#pragma unroll
    for (int m = 0; m < 4; ++m)
      af[m] = *(const bf16x8*)(As + (wr * 64 + m * 16 + lr) * 32 + lk);
#pragma unroll
    for (int n = 0; n < 4; ++n)
      bfr[n] = *(const bf16x8*)(Bs + (wc * 64 + n * 16 + lr) * 32 + lk);
#pragma unroll
    for (int m = 0; m < 4; ++m)
#pragma unroll
      for (int n = 0; n < 4; ++n)
        acc[m][n] = __builtin_amdgcn_mfma_f32_16x16x32_bf16(af[m], bfr[n], acc[m][n], 0, 0, 0);
    __syncthreads();
  }
  int rb = bm * 128 + wr * 64 + (ln >> 4) * 4;
  int cb = bn * 128 + wc * 64 + lr;
  float* Cpart = SPLITK ? ((float*)Cout + (size_t)blockIdx.z * M * N) : (float*)Cout;
#pragma unroll
  for (int m = 0; m < 4; ++m)
#pragma unroll
    for (int n = 0; n < 4; ++n)
#pragma unroll
      for (int r = 0; r < 4; ++r) {
        int row = rb + m * 16 + r;
        int col = cb + n * 16;
        float v = acc[m][n][r];
        if (EPI == 3) {
          float dtr = v + aux[col];
          v = dtr > 15.f ? dtr : __logf(1.f + __expf(dtr));
        }
        if (OUT_BF16)
          ((u16*)Cpart)[(size_t)row * N + col] = f2bf(v);
        else
          Cpart[(size_t)row * N + col] = v;
      }
}

// ---------------- reduce split-K partials -> xdbl f32, side-write dt_low bf16 ----------------
__global__ __launch_bounds__(256) void reduce_xdbl(const float* __restrict__ part,
                                                   float* __restrict__ xdbl,
                                                   u16* __restrict__ dtlow) {
  int i = blockIdx.x * 256 + threadIdx.x;
  float s = 0.f;
#pragma unroll
  for (int z = 0; z < 8; ++z) s += part[(size_t)z * (8192 * 128) + i];
  xdbl[i] = s;
  int col = i & 127;
  if (col < 64) dtlow[(size_t)(i >> 7) * 64 + col] = f2bf(s);
}

// ---------------- depthwise causal conv(4) + SiLU, 2 channels/thread ----------------
__global__ __launch_bounds__(256) void conv_silu(const u16* __restrict__ xz,
                                                 const float* __restrict__ cw,
                                                 const float* __restrict__ cb,
                                                 u16* __restrict__ out) {
  int d2 = blockIdx.x * 256 + threadIdx.x;
  int d = d2 * 2;
  int l0 = blockIdx.y * 8;
  int b = blockIdx.z;
  float w0a = cw[d * 4 + 0], w1a = cw[d * 4 + 1], w2a = cw[d * 4 + 2], w3a = cw[d * 4 + 3];
  float w0b = cw[d * 4 + 4], w1b = cw[d * 4 + 5], w2b = cw[d * 4 + 6], w3b = cw[d * 4 + 7];
  float biasa = cb[d], biasb = cb[d + 1];
  const u16* xp = xz + ((size_t)b * LSEQ) * 4096 + d;
  float xa[11], xb[11];
#pragma unroll
  for (int i = 0; i < 11; ++i) {
    int l = l0 - 3 + i;
    unsigned pk = (l >= 0) ? *(const unsigned*)(xp + (size_t)l * 4096) : 0u;
    xa[i] = bf2f((u16)(pk & 0xffffu));
    xb[i] = bf2f((u16)(pk >> 16));
  }
  u16* op = out + ((size_t)b * LSEQ + l0) * DINNER + d;
#pragma unroll
  for (int i = 0; i < 8; ++i) {
    float va = biasa + w0a * xa[i] + w1a * xa[i + 1] + w2a * xa[i + 2] + w3a * xa[i + 3];
    float vb = biasb + w0b * xb[i] + w1b * xb[i + 1] + w2b * xb[i + 2] + w3b * xb[i + 3];
    unsigned pk = (unsigned)f2bf(va * sigmoidf_(va)) |
                  ((unsigned)f2bf(vb * sigmoidf_(vb)) << 16);
    *(unsigned*)(op + (size_t)i * DINNER) = pk;
  }
}

// ---- compute a[16] = exp(dt*An[n]); fast path when An = -(n+1) (uniform branch) ----
__device__ __forceinline__ void compute_a(float dt, const float* An, bool fast, float* av) {
  if (fast) {
    float q = __expf(-dt);
    float q2 = q * q, q4 = q2 * q2;
    av[0] = q; av[1] = q2; av[2] = q2 * q; av[3] = q4;
#pragma unroll
    for (int n = 4; n < 16; ++n) av[n] = av[n - 4] * q4;
  } else {
#pragma unroll
    for (int n = 0; n < 16; ++n) av[n] = __expf(dt * An[n]);
  }
}

__device__ __forceinline__ void load_An(const float* A_log, int d, float* An, bool& fast) {
  const float4* A4 = (const float4*)(A_log + (size_t)d * 16);
  fast = true;
#pragma unroll
  for (int q = 0; q < 4; ++q) {
    float4 a = A4[q];
    An[q * 4 + 0] = -__expf(a.x);
    An[q * 4 + 1] = -__expf(a.y);
    An[q * 4 + 2] = -__expf(a.z);
    An[q * 4 + 3] = -__expf(a.w);
  }
#pragma unroll
  for (int n = 0; n < 16; ++n)
    fast = fast && (__builtin_fabsf(An[n] + (float)(n + 1)) < 1e-3f * (n + 1));
}

// ---------------- scan pass 1: local chunk scan -> H (bf16) + sdt (f32 scalar/chunk) ----
__global__ __launch_bounds__(256) void scan1(const u16* __restrict__ dtbf,
                                             const u16* __restrict__ ubf,
                                             const float* __restrict__ xdbl,
                                             const float* __restrict__ A_log,
                                             float* __restrict__ sdt_out,
                                             u16* __restrict__ H_bf) {
  int d = blockIdx.x * 256 + threadIdx.x;
  int b = blockIdx.y, c = blockIdx.z;
  size_t row0 = (size_t)b * LSEQ + c * 64;
  float An[16];
  bool fast;
  load_An(A_log, d, An, fast);
  const u16* dtp = dtbf + row0 * DINNER + d;
  const u16* up = ubf + row0 * DINNER + d;
  const float* Bp = xdbl + row0 * 128 + 64;
  float h[16];
#pragma unroll
  for (int n = 0; n < 16; ++n) h[n] = 0.f;
  float sdt = 0.f;
  float dt_c = bf2f(dtp[0]);
  float uu_c = bf2f(up[0]);
  const float4* B4 = (const float4*)Bp;
  float4 b0c = B4[0], b1c = B4[1], b2c = B4[2], b3c = B4[3];
  for (int i = 0; i < 64; ++i) {
    float dt_n = dt_c, uu_n = uu_c;
    float4 b0n = b0c, b1n = b1c, b2n = b2c, b3n = b3c;
    if (i < 63) {
      dt_n = bf2f(dtp[(size_t)(i + 1) * DINNER]);
      uu_n = bf2f(up[(size_t)(i + 1) * DINNER]);
      const float4* B4n = (const float4*)(Bp + (size_t)(i + 1) * 128);
      b0n = B4n[0]; b1n = B4n[1]; b2n = B4n[2]; b3n = B4n[3];
    }
    float dtu = dt_c * uu_c;
    sdt += dt_c;
    float Bf[16] = {b0c.x, b0c.y, b0c.z, b0c.w, b1c.x, b1c.y, b1c.z, b1c.w,
                    b2c.x, b2c.y, b2c.z, b2c.w, b3c.x, b3c.y, b3c.z, b3c.w};
    float av[16];
    compute_a(dt_c, An, fast, av);
#pragma unroll
    for (int n = 0; n < 16; ++n) h[n] = av[n] * h[n] + dtu * Bf[n];
    dt_c = dt_n; uu_c = uu_n;
    b0c = b0n; b1c = b1n; b2c = b2n; b3c = b3n;
  }
  int bd = b * DINNER + d;
  sdt_out[(size_t)c * 4096 + bd] = sdt;
  unsigned wds[8];
#pragma unroll
  for (int q = 0; q < 8; ++q)
    wds[q] = (unsigned)f2bf(h[2 * q]) | ((unsigned)f2bf(h[2 * q + 1]) << 16);
  uint4* Hp = (uint4*)(H_bf + (size_t)c * 65536 + (size_t)bd * 16);
  Hp[0] = make_uint4(wds[0], wds[1], wds[2], wds[3]);
  Hp[1] = make_uint4(wds[4], wds[5], wds[6], wds[7]);
}

// ---------------- scan pass 2: combine chunks; P recomputed from sdt (An const) ------
__global__ __launch_bounds__(256) void scan2(const u16* __restrict__ H_bf,
                                             const float* __restrict__ sdt,
                                             const float* __restrict__ A_log,
                                             u16* __restrict__ Hinit_bf) {
  int i = blockIdx.x * 256 + threadIdx.x;  // 65536 = (b*2048+d)*16 + n
  int n = i & 15, bd = i >> 4;
  int d = bd & 2047;
  float An = -__expf(A_log[d * 16 + n]);
  float h = 0.f;
  for (int c = 0; c < 64; ++c) {
    Hinit_bf[(size_t)c * 65536 + i] = f2bf(h);
    float p = __expf(An * sdt[(size_t)c * 4096 + bd]);
    h = p * h + bf2f(H_bf[(size_t)c * 65536 + i]);
  }
}

// ---------------- scan pass 3: replay with bf16 h_init; fused D-term + gate ----------
__global__ __launch_bounds__(256) void scan3(const u16* __restrict__ dtbf,
                                             const u16* __restrict__ ubf,
                                             const float* __restrict__ xdbl,
                                             const float* __restrict__ A_log,
                                             const float* __restrict__ Dp,
                                             const u16* __restrict__ xzbf,
                                             const u16* __restrict__ Hinit_bf,
                                             u16* __restrict__ ybf) {
  int d = blockIdx.x * 256 + threadIdx.x;
  int b = blockIdx.y, c = blockIdx.z;
  size_t row0 = (size_t)b * LSEQ + c * 64;
  float An[16];
  bool fast;
  load_An(A_log, d, An, fast);
  const u16* dtp = dtbf + row0 * DINNER + d;
  const u16* up = ubf + row0 * DINNER + d;
  const float* Bp = xdbl + row0 * 128 + 64;
  const float* Cp = xdbl + row0 * 128 + 80;
  const u16* gp = xzbf + row0 * 4096 + DINNER + d;
  u16* yp = ybf + row0 * DINNER + d;
  float Dv = Dp[d];
  float h[16];
  {
    const uint4* Hi4 = (const uint4*)(Hinit_bf + (size_t)c * 65536 +
                                      ((size_t)b * DINNER + d) * 16);
    uint4 p0 = Hi4[0], p1 = Hi4[1];
    unsigned wd[8] = {p0.x, p0.y, p0.z, p0.w, p1.x, p1.y, p1.z, p1.w};
#pragma unroll
    for (int q = 0; q < 8; ++q) {
      h[2 * q] = bf2f((u16)(wd[q] & 0xffffu));
      h[2 * q + 1] = bf2f((u16)(wd[q] >> 16));
    }
  }
  float dt_c = bf2f(dtp[0]);
  float uu_c = bf2f(up[0]);
  float g_c = bf2f(gp[0]);
  const float4* B4 = (const float4*)Bp;
  const float4* C4 = (const float4*)Cp;
  float4 b0c = B4[0], b1c = B4[1], b2c = B4[2], b3c = B4[3];
  float4 c0c = C4[0], c1c = C4[1], c2c = C4[2], c3c = C4[3];
  for (int i = 0; i < 64; ++i) {
    float dt_n = dt_c, uu_n = uu_c, g_n = g_c;
    float4 b0n = b0c, b1n = b1c, b2n = b2c, b3n = b3c;
    float4 c0n = c0c, c1n = c1c, c2n = c2c, c3n = c3c;
    if (i < 63) {
      dt_n = bf2f(dtp[(size_t)(i + 1) * DINNER]);
      uu_n = bf2f(up[(size_t)(i + 1) * DINNER]);
      g_n = bf2f(gp[(size_t)(i + 1) * 4096]);
      const float4* B4n = (const float4*)(Bp + (size_t)(i + 1) * 128);
      const float4* C4n = (const float4*)(Cp + (size_t)(i + 1) * 128);
      b0n = B4n[0]; b1n = B4n[1]; b2n = B4n[2]; b3n = B4n[3];
      c0n = C4n[0]; c1n = C4n[1]; c2n = C4n[2]; c3n = C4n[3];
    }
    float dtu = dt_c * uu_c;
    float Bf[16] = {b0c.x, b0c.y, b0c.z, b0c.w, b1c.x, b1c.y, b1c.z, b1c.w,
                    b2c.x, b2c.y, b2c.z, b2c.w, b3c.x, b3c.y, b3c.z, b3c.w};
    float Cf[16] = {c0c.x, c0c.y, c0c.z, c0c.w, c1c.x, c1c.y, c1c.z, c1c.w,
                    c2c.x, c2c.y, c2c.z, c2c.w, c3c.x, c3c.y, c3c.z, c3c.w};
    float av[16];
    compute_a(dt_c, An, fast, av);
    float y = 0.f;
#pragma unroll
    for (int n = 0; n < 16; ++n) {
      h[n] = av[n] * h[n] + dtu * Bf[n];
      y += h[n] * Cf[n];
    }
    yp[(size_t)i * DINNER] = f2bf((y + uu_c * Dv) * g_c);
    dt_c = dt_n; uu_c = uu_n; g_c = g_n;
    b0c = b0n; b1c = b1n; b2c = b2n; b3c = b3n;
    c0c = c0n; c1c = c1n; c2c = c2n; c3c = c3n;
  }
}

extern "C" void kernel_launch(void* const* d_in, const int* in_sizes, int n_in,
                              void* d_out, int out_size, void* d_ws, size_t ws_size,
                              hipStream_t stream) {
  const float* x = (const float*)d_in[0];
  const float* nw = (const float*)d_in[1];
  const float* nb = (const float*)d_in[2];
  const float* W_in = (const float*)d_in[3];
  const float* convw = (const float*)d_in[4];
  const float* convb = (const float*)d_in[5];
  const float* W_x = (const float*)d_in[6];
  const float* W_dt = (const float*)d_in[7];
  const float* b_dt = (const float*)d_in[8];
  const float* A_log = (const float*)d_in[9];
  const float* Dp = (const float*)d_in[10];
  const float* W_out = (const float*)d_in[11];
  float* out = (float*)d_out;

  char* wp = (char*)d_ws;
  auto alloc = [&](size_t bytes) {
    char* p = wp;
    wp += (bytes + 255) & ~(size_t)255;
    return p;
  };
  u16* xz_bf = (u16*)alloc((size_t)8192 * 4096 * 2);     // x half raw, z half silu'd
  u16* xconv_bf = (u16*)alloc((size_t)8192 * 2048 * 2);  // u
  u16* xn_bf = (u16*)alloc((size_t)8192 * 1024 * 2);
  float* xdbl = (float*)alloc((size_t)8192 * 128 * 4);
  u16* dt_bf = (u16*)alloc((size_t)8192 * 2048 * 2);     // softplus'd dt
  u16* dtlow_bf = (u16*)alloc((size_t)8192 * 64 * 2);
  u16* Wint = (u16*)alloc((size_t)4096 * 1024 * 2);
  u16* Wxt = (u16*)alloc((size_t)128 * 2048 * 2);
  u16* Wdtt = (u16*)alloc((size_t)2048 * 64 * 2);
  u16* Woutt = (u16*)alloc((size_t)1024 * 2048 * 2);
  float* P = (float*)alloc((size_t)64 * 65536 * 4);      // region reused: sdt + y overlay
  float* H = (float*)alloc((size_t)64 * 65536 * 4);      // region reused: H_bf16 + y tail
  float* Hinit = (float*)alloc((size_t)64 * 65536 * 4);  // region reused: Hinit_bf16
  // overlays:
  float* xdbl_part = (float*)P;    // split-K partials for W_x gemm, dead before scan1
  float* sdtP = (float*)P;         // scan1 out (1MB), read by scan2, dead before scan3
  u16* H_bf16 = (u16*)H;           // scan1 out (8.4MB), read by scan2, dead after
  u16* Hinit_bf16 = (u16*)Hinit;   // scan2 out (8.4MB), read by scan3
  u16* y_bf = (u16*)P;             // scan3 out (33.5MB over P∪H; sdt/H_bf dead by then)

  // weight prep (B^T bf16) + LayerNorm, single fused launch
  tc_ln_all<<<6528 + 8192, 256, 0, stream>>>(W_in, W_x, W_dt, W_out, Wint, Wxt, Wdtt, Woutt,
                                             x, nw, nb, xn_bf);

  // xz = xn @ W_in, z-half silu'd in epilogue  (256^2, 2 barriers/tile)
  gemm8p<1, 2><<<dim3(16, 32), 512, 0, stream>>>(xn_bf, Wint, xz_bf, nullptr,
                                                 8192, 4096, 1024, 2048);
  conv_silu<<<dim3(4, 512, 2), 256, 0, stream>>>(xz_bf, convw, convb, xconv_bf);
  // x_dbl = x_conv @ W_x : split-K x8 partials, then reduce (+ dt_low bf16 side-write)
  gemm_bt<0, 0, 1><<<dim3(1, 64, 8), 256, 0, stream>>>(xconv_bf, Wxt, xdbl_part, nullptr,
                                                       8192, 128, 256, 2048, 0);
  reduce_xdbl<<<4096, 256, 0, stream>>>(xdbl_part, xdbl, dtlow_bf);
  // dt = softplus(dt_low @ W_dt + b_dt)
  gemm_bt<1, 3, 0><<<dim3(16, 64), 256, 0, stream>>>(dtlow_bf, Wdtt, dt_bf, b_dt,
                                                     8192, 2048, 64, 64, 0);
  scan1<<<dim3(8, 2, 64), 256, 0, stream>>>(dt_bf, xconv_bf, xdbl, A_log, sdtP, H_bf16);
  scan2<<<256, 256, 0, stream>>>(H_bf16, sdtP, A_log, Hinit_bf16);
  scan3<<<dim3(8, 2, 64), 256, 0, stream>>>(dt_bf, xconv_bf, xdbl, A_log, Dp, xz_bf,
                                            Hinit_bf16, y_bf);
  // out = residual + y @ W_out  (128x256 tile, full machine in one round)
  gemm128_res<<<dim3(4, 64), 512, 0, stream>>>(y_bf, Woutt, out, x, 8192, 1024, 2048);
}

// Round 13
// 305.718 us; speedup vs baseline: 1.0080x; 1.0080x over previous
//
#include <hip/hip_runtime.h>

typedef unsigned short u16;
typedef __attribute__((ext_vector_type(8))) __bf16 bf16x8;
typedef __attribute__((ext_vector_type(4))) float f32x4;

#define LSEQ 4096
#define DMODEL 1024
#define DINNER 2048

__device__ __forceinline__ float bf2f(u16 u) {
  union { unsigned u; float f; } v; v.u = ((unsigned)u) << 16; return v.f;
}
__device__ __forceinline__ u16 f2bf(float f) {
  union { float f; unsigned u; } v; v.f = f;
  unsigned r = v.u + 0x7fffu + ((v.u >> 16) & 1u);
  return (u16)(r >> 16);
}
__device__ __forceinline__ void gload_lds16(const void* g, void* l) {
  __builtin_amdgcn_global_load_lds(
      (__attribute__((address_space(1))) void*)(unsigned long long)g,
      (__attribute__((address_space(3))) void*)(unsigned int)(unsigned long long)l,
      16, 0, 0);
}
__device__ __forceinline__ float sigmoidf_(float v) { return 1.f / (1.f + __expf(-v)); }

// bijective XCD swizzle (nwg % 8 == 0)
__device__ __forceinline__ void swz_block(int gx, int& bn, int& bm) {
  int lin = blockIdx.x + gridDim.x * blockIdx.y;
  int q = (gridDim.x * gridDim.y) >> 3;
  int s = (lin & 7) * q + (lin >> 3);
  bn = s % gx;
  bm = s / gx;
}

// phase boundary: barrier + scheduling fence (no instr may cross)
#define SBAR { __builtin_amdgcn_s_barrier(); __builtin_amdgcn_sched_barrier(0); }

// ---------------- fused weight transpose+cast (4 segments) + LayerNorm rows ----------------
__global__ __launch_bounds__(256) void tc_ln_all(const float* __restrict__ W_in,
                                                 const float* __restrict__ W_x,
                                                 const float* __restrict__ W_dt,
                                                 const float* __restrict__ W_out,
                                                 u16* __restrict__ o0, u16* __restrict__ o1,
                                                 u16* __restrict__ o2, u16* __restrict__ o3,
                                                 const float* __restrict__ x,
                                                 const float* __restrict__ nw,
                                                 const float* __restrict__ nb,
                                                 u16* __restrict__ xn_out) {
  int id = blockIdx.x;
  int t = threadIdx.x;
  if (id >= 6528) {
    int row = id - 6528;
    const float* xr = x + (size_t)row * DMODEL;
    float4 v = ((const float4*)xr)[t];
    float s = v.x + v.y + v.z + v.w;
    float s2 = v.x * v.x + v.y * v.y + v.z * v.z + v.w * v.w;
    for (int off = 32; off; off >>= 1) {
      s += __shfl_down(s, off);
      s2 += __shfl_down(s2, off);
    }
    __shared__ float ls[4], ls2[4];
    int wid = t >> 6;
    if ((t & 63) == 0) { ls[wid] = s; ls2[wid] = s2; }
    __syncthreads();
    s = ls[0] + ls[1] + ls[2] + ls[3];
    s2 = ls2[0] + ls2[1] + ls2[2] + ls2[3];
    float mu = s * (1.f / DMODEL);
    float var = s2 * (1.f / DMODEL) - mu * mu;
    float rs = rsqrtf(var + 1e-5f);
    float4 wv = ((const float4*)nw)[t];
    float4 bv = ((const float4*)nb)[t];
    unsigned p0 = (unsigned)f2bf((v.x - mu) * rs * wv.x + bv.x) |
                  ((unsigned)f2bf((v.y - mu) * rs * wv.y + bv.y) << 16);
    unsigned p1 = (unsigned)f2bf((v.z - mu) * rs * wv.z + bv.z) |
                  ((unsigned)f2bf((v.w - mu) * rs * wv.w + bv.w) << 16);
    ((uint2*)(xn_out + (size_t)row * DMODEL))[t] = make_uint2(p0, p1);
    return;
  }
  __shared__ float tile[32][33];
  const float* in;
  u16* out;
  int K, N, Npad, gx, bx;
  if (id < 4096)      { in = W_in;  out = o0; K = 1024; N = 4096; Npad = 4096; gx = 128; bx = id; }
  else if (id < 4352) { in = W_x;   out = o1; K = 2048; N = 96;   Npad = 128;  gx = 4;   bx = id - 4096; }
  else if (id < 4480) { in = W_dt;  out = o2; K = 64;   N = 2048; Npad = 2048; gx = 64;  bx = id - 4352; }
  else                { in = W_out; out = o3; K = 2048; N = 1024; Npad = 1024; gx = 32;  bx = id - 4480; }
  int n0 = (bx % gx) * 32, k0 = (bx / gx) * 32;
  int tx = t & 31, ty = t >> 5;
  for (int i = ty; i < 32; i += 8) {
    int k = k0 + i, n = n0 + tx;
    tile[i][tx] = (k < K && n < N) ? in[(size_t)k * N + n] : 0.f;
  }
  __syncthreads();
  for (int i = ty; i < 32; i += 8) {
    int n = n0 + i, k = k0 + tx;
    if (n < Npad && k < K) out[(size_t)n * K + k] = f2bf(tile[tx][i]);
  }
}

// ---------------- common staging helper: 8 rows x 64k, swizzle key = row&7 ----------------
__device__ __forceinline__ void stage8(const u16* grow0, int ld, int kcol0,
                                       u16* lds_u, int ln) {
  int rr = ln >> 3, kb = ln & 7;
  gload_lds16(grow0 + (size_t)rr * ld + kcol0 + ((kb ^ rr) << 3), lds_u);
}

// =====================================================================================
// gemm8p: 256x256, BK=64, 128KB LDS, 1 block/CU, 2 barriers/K-tile.
// Round-13: (a) A1 ds_reads issued at END of H0 (latency straddles the mid barrier;
// their region A-hi(b0) is NOT a target of H1's stages -> WAR-safe outstanding across
// the barrier); (b) vmcnt(6) moved BETWEEN Q(1,1) and Q(1,0): Q(1,1) uses only
// LDS-resident A1+B1 regs, so 16 MFMAs overlap the staging-drain wait; vmcnt still
// precedes the closing barrier (count semantics unchanged: 6+2+6=14 outstanding,
// retire oldest 8 = all of T+1).
// __launch_bounds__(512,2): do NOT raise min-waves (4/EU caps 128 VGPR -> acc spills).
// =====================================================================================
#define LDA_F(mh, BUF)                                                             \
  _Pragma("unroll") for (int mf = 0; mf < 4; ++mf) {                               \
    av[mf][0] = *(const bf16x8*)(qA0 + (BUF) * 16384 + ((mh) * 64 + mf * 16) * 64); \
    av[mf][1] = *(const bf16x8*)(qA1 + (BUF) * 16384 + ((mh) * 64 + mf * 16) * 64); \
  }

#define LDB_F(nh, BUF)                                                             \
  _Pragma("unroll") for (int nf = 0; nf < 2; ++nf) {                               \
    bb[nh][nf][0] = *(const bf16x8*)(qB0 + (BUF) * 16384 + ((nh) * 32 + nf * 16) * 64); \
    bb[nh][nf][1] = *(const bf16x8*)(qB1 + (BUF) * 16384 + ((nh) * 32 + nf * 16) * 64); \
  }

#define MFMA_Q(mh, nh)                                                             \
  __builtin_amdgcn_s_setprio(1);                                                   \
  _Pragma("unroll") for (int mf = 0; mf < 4; ++mf)                                 \
  _Pragma("unroll") for (int nf = 0; nf < 2; ++nf)                                 \
  _Pragma("unroll") for (int kk = 0; kk < 2; ++kk)                                 \
    acc[(mh) * 4 + mf][(nh) * 2 + nf] = __builtin_amdgcn_mfma_f32_16x16x32_bf16(   \
        av[mf][kk], bb[nh][nf][kk], acc[(mh) * 4 + mf][(nh) * 2 + nf], 0, 0, 0);   \
  __builtin_amdgcn_s_setprio(0);

#define STAGE_A(unit, kt, buf)                                                     \
  _Pragma("unroll") for (int c = 0; c < 2; ++c) {                                  \
    int g = w * 2 + c;                                                             \
    int r0 = ((g < 8) ? g * 8 : (g - 8) * 8 + 128) + (unit) * 64;                  \
    stage8(Ag + (size_t)r0 * ldK, ldK, (kt) * 64, LA + (buf) * 16384 + r0 * 64, ln); \
  }

#define STAGE_B(half, kt, buf)                                                     \
  _Pragma("unroll") for (int c = 0; c < 2; ++c) {                                  \
    int g = w * 2 + c;                                                             \
    int r0 = (g >> 2) * 64 + (half) * 32 + (g & 3) * 8;                            \
    stage8(Bg + (size_t)r0 * ldK, ldK, (kt) * 64, LB + (buf) * 16384 + r0 * 64, ln); \
  }

#define PHASES8P(T_, B0_, B1_)                                                     \
  {                                                                                \
    int kt1 = ((T_) + 1 < NT) ? (T_) + 1 : NT - 1;                                 \
    int kt2 = ((T_) + 2 < NT) ? (T_) + 2 : NT - 1;                                 \
    LDA_F(0, B0_); LDB_F(0, B0_);                                                  \
    __builtin_amdgcn_sched_barrier(0);                                             \
    LDB_F(1, B0_);                                                                 \
    STAGE_A(1, kt1, B1_);                                                          \
    MFMA_Q(0, 0);                                                                  \
    MFMA_Q(0, 1);                                                                  \
    LDA_F(1, B0_);                                                                 \
    SBAR                                                                           \
    STAGE_A(0, kt2, B0_);                                                          \
    STAGE_B(0, kt2, B0_);                                                          \
    STAGE_B(1, kt2, B0_);                                                          \
    MFMA_Q(1, 1);                                                                  \
    asm volatile("s_waitcnt vmcnt(6)" ::: "memory");                               \
    MFMA_Q(1, 0);                                                                  \
    SBAR                                                                           \
  }

template <int OUT_BF16, int EPI>  // EPI: 1 = +aux residual (f32), 2 = silu col>=cthresh
__global__ __launch_bounds__(512, 2) void gemm8p(const u16* __restrict__ A,
                                                 const u16* __restrict__ Bt,
                                                 void* __restrict__ Cout,
                                                 const float* __restrict__ aux,
                                                 int M, int N, int K, int cthresh) {
  __shared__ alignas(16) u16 lds[65536];
  u16* LA = lds;
  u16* LB = lds + 32768;
  int t = threadIdx.x;
  int w = t >> 6, ln = t & 63;
  int wm = w >> 2, wn = w & 3;
  int bn, bm;
  swz_block(gridDim.x, bn, bm);
  int lr = ln & 15, lq = ln >> 4, key = ln & 7;
  int ldK = K;
  int NT = K >> 6;
  const u16* Ag = A + (size_t)bm * 256 * ldK;
  const u16* Bg = Bt + (size_t)bn * 256 * ldK;
  const u16* qA0 = LA + (wm * 128 + lr) * 64 + ((lq ^ key) << 3);
  const u16* qA1 = LA + (wm * 128 + lr) * 64 + (((4 + lq) ^ key) << 3);
  const u16* qB0 = LB + (wn * 64 + lr) * 64 + ((lq ^ key) << 3);
  const u16* qB1 = LB + (wn * 64 + lr) * 64 + (((4 + lq) ^ key) << 3);
  f32x4 acc[8][4] = {};
  bf16x8 av[4][2], bb[2][2][2];

  STAGE_A(0, 0, 0); STAGE_B(0, 0, 0); STAGE_B(1, 0, 0); STAGE_A(1, 0, 0);
  int k1 = NT > 1 ? 1 : 0;
  STAGE_A(0, k1, 1); STAGE_B(0, k1, 1); STAGE_B(1, k1, 1);
  asm volatile("s_waitcnt vmcnt(6)" ::: "memory");
  SBAR

  for (int TT = 0; TT < NT; TT += 2) {  // NT is even (K multiple of 128)
    PHASES8P(TT, 0, 1)
    PHASES8P(TT + 1, 1, 0)
  }

  int crow0 = bm * 256 + wm * 128;
  int ccol0 = bn * 256 + wn * 64;
#pragma unroll
  for (int mf = 0; mf < 8; ++mf)
#pragma unroll
    for (int nf = 0; nf < 4; ++nf)
#pragma unroll
      for (int r = 0; r < 4; ++r) {
        int row = crow0 + mf * 16 + lq * 4 + r;
        int col = ccol0 + nf * 16 + lr;
        float v = acc[mf][nf][r];
        if (EPI == 1) v += aux[(size_t)row * N + col];
        if (EPI == 2 && col >= cthresh) v = v * sigmoidf_(v);
        if (OUT_BF16)
          ((u16*)Cout)[(size_t)row * N + col] = f2bf(v);
        else
          ((float*)Cout)[(size_t)row * N + col] = v;
      }
}

// =====================================================================================
// gemm128_res: BM=128 x BN=256, BK=64, 96KB LDS, 2 barriers/tile, residual fused, f32.
// Same round-13 restructure; counted wait vmcnt(5) between Q(1,1) and Q(1,0).
// =====================================================================================
#define LDA128(mh, BUF)                                                            \
  _Pragma("unroll") for (int mf2 = 0; mf2 < 2; ++mf2) {                            \
    av[mf2][0] = *(const bf16x8*)(rA0 + (BUF) * 8192 + ((mh) * 32 + mf2 * 16) * 64); \
    av[mf2][1] = *(const bf16x8*)(rA1 + (BUF) * 8192 + ((mh) * 32 + mf2 * 16) * 64); \
  }

#define LDB128(nh, BUF, B_)                                                        \
  _Pragma("unroll") for (int nf2 = 0; nf2 < 2; ++nf2) {                            \
    B_[nf2][0] = *(const bf16x8*)(rB0 + (BUF) * 16384 + ((nh) * 32 + nf2 * 16) * 64); \
    B_[nf2][1] = *(const bf16x8*)(rB1 + (BUF) * 16384 + ((nh) * 32 + nf2 * 16) * 64); \
  }

#define MFMA_Q128(mh, nh, B_)                                                      \
  __builtin_amdgcn_s_setprio(1);                                                   \
  _Pragma("unroll") for (int mf2 = 0; mf2 < 2; ++mf2)                              \
  _Pragma("unroll") for (int nf2 = 0; nf2 < 2; ++nf2)                              \
  _Pragma("unroll") for (int kk = 0; kk < 2; ++kk)                                 \
    acc[(mh) * 2 + mf2][(nh) * 2 + nf2] = __builtin_amdgcn_mfma_f32_16x16x32_bf16( \
        av[mf2][kk], B_[nf2][kk], acc[(mh) * 2 + mf2][(nh) * 2 + nf2], 0, 0, 0);   \
  __builtin_amdgcn_s_setprio(0);

#define STAGE_A128(unit, kt, buf)                                                  \
  {                                                                                \
    int r0 = (w >> 2) * 64 + (unit) * 32 + (w & 3) * 8;                            \
    stage8(Ag + (size_t)r0 * ldK, ldK, (kt) * 64, LA + (buf) * 8192 + r0 * 64, ln); \
  }

#define STAGE_B128(half, kt, buf)                                                  \
  _Pragma("unroll") for (int c = 0; c < 2; ++c) {                                  \
    int g = w * 2 + c;                                                             \
    int r0 = (g >> 2) * 64 + (half) * 32 + (g & 3) * 8;                            \
    stage8(Bg + (size_t)r0 * ldK, ldK, (kt) * 64, LB + (buf) * 16384 + r0 * 64, ln); \
  }

#define PHASES128(T_, B0_, B1_)                                                    \
  {                                                                                \
    int kt1 = ((T_) + 1 < NT) ? (T_) + 1 : NT - 1;                                 \
    int kt2 = ((T_) + 2 < NT) ? (T_) + 2 : NT - 1;                                 \
    LDA128(0, B0_);                                                                \
    LDB128(0, B0_, bbl);                                                           \
    __builtin_amdgcn_sched_barrier(0);                                             \
    LDB128(1, B0_, bbh);                                                           \
    STAGE_A128(1, kt1, B1_);                                                       \
    MFMA_Q128(0, 0, bbl);                                                          \
    MFMA_Q128(0, 1, bbh);                                                          \
    LDA128(1, B0_);                                                                \
    SBAR                                                                           \
    STAGE_A128(0, kt2, B0_);                                                       \
    STAGE_B128(0, kt2, B0_);                                                       \
    STAGE_B128(1, kt2, B0_);                                                       \
    MFMA_Q128(1, 1, bbh);                                                          \
    asm volatile("s_waitcnt vmcnt(5)" ::: "memory");                               \
    MFMA_Q128(1, 0, bbl);                                                          \
    SBAR                                                                           \
  }

__global__ __launch_bounds__(512, 2) void gemm128_res(const u16* __restrict__ A,
                                                      const u16* __restrict__ Bt,
                                                      float* __restrict__ Cout,
                                                      const float* __restrict__ res,
                                                      int M, int N, int K) {
  __shared__ alignas(16) u16 lds[49152];
  u16* LA = lds;
  u16* LB = lds + 16384;
  int t = threadIdx.x;
  int w = t >> 6, ln = t & 63;
  int wm = w >> 2, wn = w & 3;
  int bn, bm;
  swz_block(gridDim.x, bn, bm);
  int lr = ln & 15, lq = ln >> 4, key = ln & 7;
  int ldK = K;
  int NT = K >> 6;
  const u16* Ag = A + (size_t)bm * 128 * ldK;
  const u16* Bg = Bt + (size_t)bn * 256 * ldK;
  const u16* rA0 = LA + (wm * 64 + lr) * 64 + ((lq ^ key) << 3);
  const u16* rA1 = LA + (wm * 64 + lr) * 64 + (((4 + lq) ^ key) << 3);
  const u16* rB0 = LB + (wn * 64 + lr) * 64 + ((lq ^ key) << 3);
  const u16* rB1 = LB + (wn * 64 + lr) * 64 + (((4 + lq) ^ key) << 3);
  f32x4 acc[4][4] = {};
  bf16x8 av[2][2], bbl[2][2], bbh[2][2];

  STAGE_A128(0, 0, 0); STAGE_B128(0, 0, 0); STAGE_B128(1, 0, 0); STAGE_A128(1, 0, 0);
  int k1 = NT > 1 ? 1 : 0;
  STAGE_A128(0, k1, 1); STAGE_B128(0, k1, 1); STAGE_B128(1, k1, 1);
  asm volatile("s_waitcnt vmcnt(5)" ::: "memory");
  SBAR

  for (int TT = 0; TT < NT; TT += 2) {
    PHASES128(TT, 0, 1)
    PHASES128(TT + 1, 1, 0)
  }

  int crow0 = bm * 128 + wm * 64;
  int ccol0 = bn * 256 + wn * 64;
#pragma unroll
  for (int mf = 0; mf < 4; ++mf)
#pragma unroll
    for (int nf = 0; nf < 4; ++nf)
#pragma unroll
      for (int r = 0; r < 4; ++r) {
        int row = crow0 + mf * 16 + lq * 4 + r;
        int col = ccol0 + nf * 16 + lr;
        Cout[(size_t)row * N + col] = acc[mf][nf][r] + res[(size_t)row * N + col];
      }
}

// ---------------- 128x128 bf16 GEMM (small shapes) ----------------
template <int OUT_BF16, int EPI, int SPLITK>
__global__ __launch_bounds__(256) void gemm_bt(const u16* __restrict__ A,
                                               const u16* __restrict__ Bt,
                                               void* __restrict__ Cout,
                                               const float* __restrict__ aux,
                                               int M, int N, int K, int ld, int cthresh) {
  __shared__ alignas(16) u16 As[128 * 32];
  __shared__ alignas(16) u16 Bs[128 * 32];
  int t = threadIdx.x;
  int w = t >> 6, ln = t & 63;
  int wr = w >> 1, wc = w & 1;
  int bm = blockIdx.y, bn = blockIdx.x;
  int lr = ln & 15, lk = (ln >> 4) * 8;
  f32x4 acc[4][4] = {};
  int kz = SPLITK ? blockIdx.z * K : 0;
  const u16* Abase = A + (size_t)bm * 128 * ld + kz;
  const u16* Bbase = Bt + (size_t)bn * 128 * ld + kz;
  for (int k0 = 0; k0 < K; k0 += 32) {
#pragma unroll
    for (int c = 0; c < 2; ++c) {
      int chunk = w * 2 + c;
      int ee = chunk * 512 + ln * 8;
      int row = ee >> 5, col = ee & 31;
      gload_lds16(Abase + (size_t)row * ld + k0 + col, As + chunk * 512);
      gload_lds16(Bbase + (size_t)row * ld + k0 + col, Bs + chunk * 512);
    }
    __syncthreads();
    bf16x8 af[4], bfr[4];
#pragma unroll
    for (int m = 0; m < 4; ++m)
      af[m] = *(const bf16x8*)(As + (wr * 64 + m * 16 + lr) * 32 + lk);
#pragma unroll
    for (int n = 0; n < 4; ++n)
      bfr[n] = *(const bf16x8*)(Bs + (wc * 64 + n * 16 + lr) * 32 + lk);
#pragma unroll
    for (int m = 0; m < 4; ++m)
#pragma unroll
      for (int n = 0; n < 4; ++n)
        acc[m][n] = __builtin_amdgcn_mfma_f32_16x16x32_bf16(af[m], bfr[n], acc[m][n], 0, 0, 0);
    __syncthreads();
  }
  int rb = bm * 128 + wr * 64 + (ln >> 4) * 4;
  int cb = bn * 128 + wc * 64 + lr;
  float* Cpart = SPLITK ? ((float*)Cout + (size_t)blockIdx.z * M * N) : (float*)Cout;
#pragma unroll
  for (int m = 0; m < 4; ++m)
#pragma unroll
    for (int n = 0; n < 4; ++n)
#pragma unroll
      for (int r = 0; r < 4; ++r) {
        int row = rb + m * 16 + r;
        int col = cb + n * 16;
        float v = acc[m][n][r];
        if (EPI == 3) {
          float dtr = v + aux[col];
          v = dtr > 15.f ? dtr : __logf(1.f + __expf(dtr));
        }
        if (OUT_BF16)
          ((u16*)Cpart)[(size_t)row * N + col] = f2bf(v);
        else
          Cpart[(size_t)row * N + col] = v;
      }
}

// ---------------- reduce split-K partials -> xdbl f32, side-write dt_low bf16 ----------------
__global__ __launch_bounds__(256) void reduce_xdbl(const float* __restrict__ part,
                                                   float* __restrict__ xdbl,
                                                   u16* __restrict__ dtlow) {
  int i = blockIdx.x * 256 + threadIdx.x;
  float s = 0.f;
#pragma unroll
  for (int z = 0; z < 8; ++z) s += part[(size_t)z * (8192 * 128) + i];
  xdbl[i] = s;
  int col = i & 127;
  if (col < 64) dtlow[(size_t)(i >> 7) * 64 + col] = f2bf(s);
}

// ---------------- depthwise causal conv(4) + SiLU, 2 channels/thread ----------------
__global__ __launch_bounds__(256) void conv_silu(const u16* __restrict__ xz,
                                                 const float* __restrict__ cw,
                                                 const float* __restrict__ cb,
                                                 u16* __restrict__ out) {
  int d2 = blockIdx.x * 256 + threadIdx.x;
  int d = d2 * 2;
  int l0 = blockIdx.y * 8;
  int b = blockIdx.z;
  float w0a = cw[d * 4 + 0], w1a = cw[d * 4 + 1], w2a = cw[d * 4 + 2], w3a = cw[d * 4 + 3];
  float w0b = cw[d * 4 + 4], w1b = cw[d * 4 + 5], w2b = cw[d * 4 + 6], w3b = cw[d * 4 + 7];
  float biasa = cb[d], biasb = cb[d + 1];
  const u16* xp = xz + ((size_t)b * LSEQ) * 4096 + d;
  float xa[11], xb[11];
#pragma unroll
  for (int i = 0; i < 11; ++i) {
    int l = l0 - 3 + i;
    unsigned pk = (l >= 0) ? *(const unsigned*)(xp + (size_t)l * 4096) : 0u;
    xa[i] = bf2f((u16)(pk & 0xffffu));
    xb[i] = bf2f((u16)(pk >> 16));
  }
  u16* op = out + ((size_t)b * LSEQ + l0) * DINNER + d;
#pragma unroll
  for (int i = 0; i < 8; ++i) {
    float va = biasa + w0a * xa[i] + w1a * xa[i + 1] + w2a * xa[i + 2] + w3a * xa[i + 3];
    float vb = biasb + w0b * xb[i] + w1b * xb[i + 1] + w2b * xb[i + 2] + w3b * xb[i + 3];
    unsigned pk = (unsigned)f2bf(va * sigmoidf_(va)) |
                  ((unsigned)f2bf(vb * sigmoidf_(vb)) << 16);
    *(unsigned*)(op + (size_t)i * DINNER) = pk;
  }
}

// ---- compute a[16] = exp(dt*An[n]); fast path when An = -(n+1) (uniform branch) ----
__device__ __forceinline__ void compute_a(float dt, const float* An, bool fast, float* av) {
  if (fast) {
    float q = __expf(-dt);
    float q2 = q * q, q4 = q2 * q2;
    av[0] = q; av[1] = q2; av[2] = q2 * q; av[3] = q4;
#pragma unroll
    for (int n = 4; n < 16; ++n) av[n] = av[n - 4] * q4;
  } else {
#pragma unroll
    for (int n = 0; n < 16; ++n) av[n] = __expf(dt * An[n]);
  }
}

__device__ __forceinline__ void load_An(const float* A_log, int d, float* An, bool& fast) {
  const float4* A4 = (const float4*)(A_log + (size_t)d * 16);
  fast = true;
#pragma unroll
  for (int q = 0; q < 4; ++q) {
    float4 a = A4[q];
    An[q * 4 + 0] = -__expf(a.x);
    An[q * 4 + 1] = -__expf(a.y);
    An[q * 4 + 2] = -__expf(a.z);
    An[q * 4 + 3] = -__expf(a.w);
  }
#pragma unroll
  for (int n = 0; n < 16; ++n)
    fast = fast && (__builtin_fabsf(An[n] + (float)(n + 1)) < 1e-3f * (n + 1));
}

// ---------------- scan pass 1: local chunk scan -> H (bf16) + sdt (f32 scalar/chunk) ----
__global__ __launch_bounds__(256) void scan1(const u16* __restrict__ dtbf,
                                             const u16* __restrict__ ubf,
                                             const float* __restrict__ xdbl,
                                             const float* __restrict__ A_log,
                                             float* __restrict__ sdt_out,
                                             u16* __restrict__ H_bf) {
  int d = blockIdx.x * 256 + threadIdx.x;
  int b = blockIdx.y, c = blockIdx.z;
  size_t row0 = (size_t)b * LSEQ + c * 64;
  float An[16];
  bool fast;
  load_An(A_log, d, An, fast);
  const u16* dtp = dtbf + row0 * DINNER + d;
  const u16* up = ubf + row0 * DINNER + d;
  const float* Bp = xdbl + row0 * 128 + 64;
  float h[16];
#pragma unroll
  for (int n = 0; n < 16; ++n) h[n] = 0.f;
  float sdt = 0.f;
  float dt_c = bf2f(dtp[0]);
  float uu_c = bf2f(up[0]);
  const float4* B4 = (const float4*)Bp;
  float4 b0c = B4[0], b1c = B4[1], b2c = B4[2], b3c = B4[3];
  for (int i = 0; i < 64; ++i) {
    float dt_n = dt_c, uu_n = uu_c;
    float4 b0n = b0c, b1n = b1c, b2n = b2c, b3n = b3c;
    if (i < 63) {
      dt_n = bf2f(dtp[(size_t)(i + 1) * DINNER]);
      uu_n = bf2f(up[(size_t)(i + 1) * DINNER]);
      const float4* B4n = (const float4*)(Bp + (size_t)(i + 1) * 128);
      b0n = B4n[0]; b1n = B4n[1]; b2n = B4n[2]; b3n = B4n[3];
    }
    float dtu = dt_c * uu_c;
    sdt += dt_c;
    float Bf[16] = {b0c.x, b0c.y, b0c.z, b0c.w, b1c.x, b1c.y, b1c.z, b1c.w,
                    b2c.x, b2c.y, b2c.z, b2c.w, b3c.x, b3c.y, b3c.z, b3c.w};
    float av[16];
    compute_a(dt_c, An, fast, av);
#pragma unroll
    for (int n = 0; n < 16; ++n) h[n] = av[n] * h[n] + dtu * Bf[n];
    dt_c = dt_n; uu_c = uu_n;
    b0c = b0n; b1c = b1n; b2c = b2n; b3c = b3n;
  }
  int bd = b * DINNER + d;
  sdt_out[(size_t)c * 4096 + bd] = sdt;
  unsigned wds[8];
#pragma unroll
  for (int q = 0; q < 8; ++q)
    wds[q] = (unsigned)f2bf(h[2 * q]) | ((unsigned)f2bf(h[2 * q + 1]) << 16);
  uint4* Hp = (uint4*)(H_bf + (size_t)c * 65536 + (size_t)bd * 16);
  Hp[0] = make_uint4(wds[0], wds[1], wds[2], wds[3]);
  Hp[1] = make_uint4(wds[4], wds[5], wds[6], wds[7]);
}

// ---------------- scan pass 2: combine chunks; P recomputed from sdt (An const) ------
__global__ __launch_bounds__(256) void scan2(const u16* __restrict__ H_bf,
                                             const float* __restrict__ sdt,
                                             const float* __restrict__ A_log,
                                             u16* __restrict__ Hinit_bf) {
  int i = blockIdx.x * 256 + threadIdx.x;  // 65536 = (b*2048+d)*16 + n
  int n = i & 15, bd = i >> 4;
  int d = bd & 2047;
  float An = -__expf(A_log[d * 16 + n]);
  float h = 0.f;
  for (int c = 0; c < 64; ++c) {
    Hinit_bf[(size_t)c * 65536 + i] = f2bf(h);
    float p = __expf(An * sdt[(size_t)c * 4096 + bd]);
    h = p * h + bf2f(H_bf[(size_t)c * 65536 + i]);
  }
}

// ---------------- scan pass 3: replay with bf16 h_init; fused D-term + gate ----------
__global__ __launch_bounds__(256) void scan3(const u16* __restrict__ dtbf,
                                             const u16* __restrict__ ubf,
                                             const float* __restrict__ xdbl,
                                             const float* __restrict__ A_log,
                                             const float* __restrict__ Dp,
                                             const u16* __restrict__ xzbf,
                                             const u16* __restrict__ Hinit_bf,
                                             u16* __restrict__ ybf) {
  int d = blockIdx.x * 256 + threadIdx.x;
  int b = blockIdx.y, c = blockIdx.z;
  size_t row0 = (size_t)b * LSEQ + c * 64;
  float An[16];
  bool fast;
  load_An(A_log, d, An, fast);
  const u16* dtp = dtbf + row0 * DINNER + d;
  const u16* up = ubf + row0 * DINNER + d;
  const float* Bp = xdbl + row0 * 128 + 64;
  const float* Cp = xdbl + row0 * 128 + 80;
  const u16* gp = xzbf + row0 * 4096 + DINNER + d;
  u16* yp = ybf + row0 * DINNER + d;
  float Dv = Dp[d];
  float h[16];
  {
    const uint4* Hi4 = (const uint4*)(Hinit_bf + (size_t)c * 65536 +
                                      ((size_t)b * DINNER + d) * 16);
    uint4 p0 = Hi4[0], p1 = Hi4[1];
    unsigned wd[8] = {p0.x, p0.y, p0.z, p0.w, p1.x, p1.y, p1.z, p1.w};
#pragma unroll
    for (int q = 0; q < 8; ++q) {
      h[2 * q] = bf2f((u16)(wd[q] & 0xffffu));
      h[2 * q + 1] = bf2f((u16)(wd[q] >> 16));
    }
  }
  float dt_c = bf2f(dtp[0]);
  float uu_c = bf2f(up[0]);
  float g_c = bf2f(gp[0]);
  const float4* B4 = (const float4*)Bp;
  const float4* C4 = (const float4*)Cp;
  float4 b0c = B4[0], b1c = B4[1], b2c = B4[2], b3c = B4[3];
  float4 c0c = C4[0], c1c = C4[1], c2c = C4[2], c3c = C4[3];
  for (int i = 0; i < 64; ++i) {
    float dt_n = dt_c, uu_n = uu_c, g_n = g_c;
    float4 b0n = b0c, b1n = b1c, b2n = b2c, b3n = b3c;
    float4 c0n = c0c, c1n = c1c, c2n = c2c, c3n = c3c;
    if (i < 63) {
      dt_n = bf2f(dtp[(size_t)(i + 1) * DINNER]);
      uu_n = bf2f(up[(size_t)(i + 1) * DINNER]);
      g_n = bf2f(gp[(size_t)(i + 1) * 4096]);
      const float4* B4n = (const float4*)(Bp + (size_t)(i + 1) * 128);
      const float4* C4n = (const float4*)(Cp + (size_t)(i + 1) * 128);
      b0n = B4n[0]; b1n = B4n[1]; b2n = B4n[2]; b3n = B4n[3];
      c0n = C4n[0]; c1n = C4n[1]; c2n = C4n[2]; c3n = C4n[3];
    }
    float dtu = dt_c * uu_c;
    float Bf[16] = {b0c.x, b0c.y, b0c.z, b0c.w, b1c.x, b1c.y, b1c.z, b1c.w,
                    b2c.x, b2c.y, b2c.z, b2c.w, b3c.x, b3c.y, b3c.z, b3c.w};
    float Cf[16] = {c0c.x, c0c.y, c0c.z, c0c.w, c1c.x, c1c.y, c1c.z, c1c.w,
                    c2c.x, c2c.y, c2c.z, c2c.w, c3c.x, c3c.y, c3c.z, c3c.w};
    float av[16];
    compute_a(dt_c, An, fast, av);
    float y = 0.f;
#pragma unroll
    for (int n = 0; n < 16; ++n) {
      h[n] = av[n] * h[n] + dtu * Bf[n];
      y += h[n] * Cf[n];
    }
    yp[(size_t)i * DINNER] = f2bf((y + uu_c * Dv) * g_c);
    dt_c = dt_n; uu_c = uu_n; g_c = g_n;
    b0c = b0n; b1c = b1n; b2c = b2n; b3c = b3n;
    c0c = c0n; c1c = c1n; c2c = c2n; c3c = c3n;
  }
}

extern "C" void kernel_launch(void* const* d_in, const int* in_sizes, int n_in,
                              void* d_out, int out_size, void* d_ws, size_t ws_size,
                              hipStream_t stream) {
  const float* x = (const float*)d_in[0];
  const float* nw = (const float*)d_in[1];
  const float* nb = (const float*)d_in[2];
  const float* W_in = (const float*)d_in[3];
  const float* convw = (const float*)d_in[4];
  const float* convb = (const float*)d_in[5];
  const float* W_x = (const float*)d_in[6];
  const float* W_dt = (const float*)d_in[7];
  const float* b_dt = (const float*)d_in[8];
  const float* A_log = (const float*)d_in[9];
  const float* Dp = (const float*)d_in[10];
  const float* W_out = (const float*)d_in[11];
  float* out = (float*)d_out;

  char* wp = (char*)d_ws;
  auto alloc = [&](size_t bytes) {
    char* p = wp;
    wp += (bytes + 255) & ~(size_t)255;
    return p;
  };
  u16* xz_bf = (u16*)alloc((size_t)8192 * 4096 * 2);     // x half raw, z half silu'd
  u16* xconv_bf = (u16*)alloc((size_t)8192 * 2048 * 2);  // u
  u16* xn_bf = (u16*)alloc((size_t)8192 * 1024 * 2);
  float* xdbl = (float*)alloc((size_t)8192 * 128 * 4);
  u16* dt_bf = (u16*)alloc((size_t)8192 * 2048 * 2);     // softplus'd dt
  u16* dtlow_bf = (u16*)alloc((size_t)8192 * 64 * 2);
  u16* Wint = (u16*)alloc((size_t)4096 * 1024 * 2);
  u16* Wxt = (u16*)alloc((size_t)128 * 2048 * 2);
  u16* Wdtt = (u16*)alloc((size_t)2048 * 64 * 2);
  u16* Woutt = (u16*)alloc((size_t)1024 * 2048 * 2);
  float* P = (float*)alloc((size_t)64 * 65536 * 4);
  float* H = (float*)alloc((size_t)64 * 65536 * 4);
  float* Hinit = (float*)alloc((size_t)64 * 65536 * 4);
  // overlays:
  float* xdbl_part = (float*)P;    // split-K partials for W_x gemm, dead before scan1
  float* sdtP = (float*)P;         // scan1 out (1MB), read by scan2, dead before scan3
  u16* H_bf16 = (u16*)H;           // scan1 out (8.4MB), read by scan2, dead after
  u16* Hinit_bf16 = (u16*)Hinit;   // scan2 out (8.4MB), read by scan3
  u16* y_bf = (u16*)P;             // scan3 out (33.5MB over P∪H; sdt/H_bf dead by then)

  // weight prep (B^T bf16) + LayerNorm, single fused launch
  tc_ln_all<<<6528 + 8192, 256, 0, stream>>>(W_in, W_x, W_dt, W_out, Wint, Wxt, Wdtt, Woutt,
                                             x, nw, nb, xn_bf);

  // xz = xn @ W_in, z-half silu'd in epilogue  (256^2, 2 barriers/tile)
  gemm8p<1, 2><<<dim3(16, 32), 512, 0, stream>>>(xn_bf, Wint, xz_bf, nullptr,
                                                 8192, 4096, 1024, 2048);
  conv_silu<<<dim3(4, 512, 2), 256, 0, stream>>>(xz_bf, convw, convb, xconv_bf);
  // x_dbl = x_conv @ W_x : split-K x8 partials, then reduce (+ dt_low bf16 side-write)
  gemm_bt<0, 0, 1><<<dim3(1, 64, 8), 256, 0, stream>>>(xconv_bf, Wxt, xdbl_part, nullptr,
                                                       8192, 128, 256, 2048, 0);
  reduce_xdbl<<<4096, 256, 0, stream>>>(xdbl_part, xdbl, dtlow_bf);
  // dt = softplus(dt_low @ W_dt + b_dt)
  gemm_bt<1, 3, 0><<<dim3(16, 64), 256, 0, stream>>>(dtlow_bf, Wdtt, dt_bf, b_dt,
                                                     8192, 2048, 64, 64, 0);
  scan1<<<dim3(8, 2, 64), 256, 0, stream>>>(dt_bf, xconv_bf, xdbl, A_log, sdtP, H_bf16);
  scan2<<<256, 256, 0, stream>>>(H_bf16, sdtP, A_log, Hinit_bf16);
  scan3<<<dim3(8, 2, 64), 256, 0, stream>>>(dt_bf, xconv_bf, xdbl, A_log, Dp, xz_bf,
                                            Hinit_bf16, y_bf);
  // out = residual + y @ W_out  (128x256 tile, full machine in one round)
  gemm128_res<<<dim3(4, 64), 512, 0, stream>>>(y_bf, Woutt, out, x, 8192, 1024, 2048);
}